// Round 2
// baseline (2326.532 us; speedup 1.0000x reference)
//
#include <hip/hip_runtime.h>
#include <cstdint>

#define E_NUM 640000
#define NTOT 32000
#define RNUM 44
#define NB (RNUM*NTOT)   // 1,408,000 (rel,dst) bins

typedef _Float16 f16x8 __attribute__((ext_vector_type(8)));
typedef _Float16 f16x4 __attribute__((ext_vector_type(4)));
typedef float    f32x4 __attribute__((ext_vector_type(4)));

__device__ __forceinline__ float gelu_f(float v) {
  return 0.5f * v * (1.0f + erff(v * 0.70710678118654752f));
}

// ---------------- utility kernels ----------------

__global__ void zero_int_k(int* __restrict__ p, int n) {
  int i = blockIdx.x * 256 + threadIdx.x;
  if (i < n) p[i] = 0;
}

__global__ void hist_k(const int* __restrict__ ei, const int* __restrict__ rel,
                       int* __restrict__ hist) {
  int e = blockIdx.x * 256 + threadIdx.x;
  if (e < E_NUM) {
    int d = ei[E_NUM + e];
    int r = rel[e];
    atomicAdd(&hist[r * NTOT + d], 1);
  }
}

// exclusive scan, 1024 items/block, in-place; block totals -> partials
__global__ void scan1_k(int* __restrict__ data, int* __restrict__ partials, int n) {
  __shared__ int ws[4];
  const int t = threadIdx.x;
  const int base = blockIdx.x * 1024 + t * 4;
  int v0 = 0, v1 = 0, v2 = 0, v3 = 0;
  if (base + 3 < n) {
    int4 u = *(const int4*)(data + base);
    v0 = u.x; v1 = u.y; v2 = u.z; v3 = u.w;
  } else if (base < n) {
    v0 = data[base];
    if (base + 1 < n) v1 = data[base + 1];
    if (base + 2 < n) v2 = data[base + 2];
  }
  const int tsum = v0 + v1 + v2 + v3;
  int incl = tsum;
  #pragma unroll
  for (int off = 1; off < 64; off <<= 1) {
    int u = __shfl_up(incl, off, 64);
    if ((t & 63) >= off) incl += u;
  }
  if ((t & 63) == 63) ws[t >> 6] = incl;
  __syncthreads();
  int wofs = 0;
  #pragma unroll
  for (int wv = 0; wv < 3; ++wv) if (wv < (t >> 6)) wofs += ws[wv];
  const int excl = wofs + incl - tsum;
  if (base + 3 < n) {
    int4 o; o.x = excl; o.y = excl + v0; o.z = excl + v0 + v1; o.w = excl + v0 + v1 + v2;
    *(int4*)(data + base) = o;
  } else if (base < n) {
    data[base] = excl;
    if (base + 1 < n) data[base + 1] = excl + v0;
    if (base + 2 < n) data[base + 2] = excl + v0 + v1;
  }
  if (t == 255) partials[blockIdx.x] = wofs + incl;
}

// single-block exclusive scan of partials (n <= a few thousand)
__global__ void scan2_k(int* __restrict__ p, int n) {
  __shared__ int ws[4];
  __shared__ int carryS;
  const int t = threadIdx.x;
  if (t == 0) carryS = 0;
  for (int chunk = 0; chunk < n; chunk += 1024) {
    __syncthreads();
    const int carry = carryS;
    const int base = chunk + t * 4;
    int v0 = 0, v1 = 0, v2 = 0, v3 = 0;
    if (base     < n) v0 = p[base];
    if (base + 1 < n) v1 = p[base + 1];
    if (base + 2 < n) v2 = p[base + 2];
    if (base + 3 < n) v3 = p[base + 3];
    const int tsum = v0 + v1 + v2 + v3;
    int incl = tsum;
    #pragma unroll
    for (int off = 1; off < 64; off <<= 1) {
      int u = __shfl_up(incl, off, 64);
      if ((t & 63) >= off) incl += u;
    }
    if ((t & 63) == 63) ws[t >> 6] = incl;
    __syncthreads();
    int wofs = 0;
    #pragma unroll
    for (int wv = 0; wv < 3; ++wv) if (wv < (t >> 6)) wofs += ws[wv];
    const int excl = carry + wofs + incl - tsum;
    if (base     < n) p[base]     = excl;
    if (base + 1 < n) p[base + 1] = excl + v0;
    if (base + 2 < n) p[base + 2] = excl + v0 + v1;
    if (base + 3 < n) p[base + 3] = excl + v0 + v1 + v2;
    __syncthreads();
    if (t == 255) carryS = carry + wofs + incl;
  }
}

__global__ void scan3_k(int* __restrict__ data, const int* __restrict__ partials, int n) {
  const int base = blockIdx.x * 1024 + threadIdx.x * 4;
  const int pofs = partials[blockIdx.x];
  if (base + 3 < n) {
    int4 u = *(const int4*)(data + base);
    u.x += pofs; u.y += pofs; u.z += pofs; u.w += pofs;
    *(int4*)(data + base) = u;
  } else if (base < n) {
    data[base] += pofs;
    if (base + 1 < n) data[base + 1] += pofs;
    if (base + 2 < n) data[base + 2] += pofs;
  }
}

__global__ void scatter_k(const int* __restrict__ ei, const int* __restrict__ rel,
                          int* __restrict__ cursor, int* __restrict__ sortedSrc) {
  int e = blockIdx.x * 256 + threadIdx.x;
  if (e < E_NUM) {
    int s = ei[e], d = ei[E_NUM + e], r = rel[e];
    int pos = atomicAdd(&cursor[r * NTOT + d], 1);
    sortedSrc[pos] = s;
  }
}

// ---------------- batchnorm ----------------

template<int C>
__global__ void bn_partial_k(const float* __restrict__ x, float* __restrict__ acc) {
  const int t = threadIdx.x;
  const int r0 = blockIdx.x * 128;
  constexpr int CC = C / 256;
  float s[CC], q[CC];
  #pragma unroll
  for (int cc = 0; cc < CC; ++cc) { s[cc] = 0.f; q[cc] = 0.f; }
  for (int r = 0; r < 128; ++r) {
    const float* row = x + (size_t)(r0 + r) * C + t;
    #pragma unroll
    for (int cc = 0; cc < CC; ++cc) { float v = row[cc * 256]; s[cc] += v; q[cc] += v * v; }
  }
  #pragma unroll
  for (int cc = 0; cc < CC; ++cc) {
    atomicAdd(&acc[t + cc * 256], s[cc]);
    atomicAdd(&acc[C + t + cc * 256], q[cc]);
  }
}

__global__ void bn_final_k(const float* __restrict__ acc, const float* __restrict__ gamma,
                           const float* __restrict__ beta, float* __restrict__ ss, int C) {
  int c = threadIdx.x;
  if (c < C) {
    float mean = acc[c] * (1.0f / 32000.0f);
    float var  = acc[C + c] * (1.0f / 32000.0f) - mean * mean;
    float sc = gamma[c] / sqrtf(var + 1e-5f);
    ss[c] = sc;
    ss[C + c] = beta[c] - mean * sc;
  }
}

// h16 = fp16(gelu(bn(x))), x16 = fp16(x);  C=256
__global__ void bn1_apply_k(const float* __restrict__ x, const float* __restrict__ ss,
                            _Float16* __restrict__ h16, _Float16* __restrict__ x16) {
  const int i = blockIdx.x * 256 + threadIdx.x;      // < NTOT*256/4
  const float4 v = ((const float4*)x)[i];
  const int c4 = i & 63;
  const float4 sc = ((const float4*)ss)[c4];
  const float4 sh = ((const float4*)(ss + 256))[c4];
  f16x4 hv, xv;
  hv[0] = (_Float16)gelu_f(v.x * sc.x + sh.x);
  hv[1] = (_Float16)gelu_f(v.y * sc.y + sh.y);
  hv[2] = (_Float16)gelu_f(v.z * sc.z + sh.z);
  hv[3] = (_Float16)gelu_f(v.w * sc.w + sh.w);
  xv[0] = (_Float16)v.x; xv[1] = (_Float16)v.y; xv[2] = (_Float16)v.z; xv[3] = (_Float16)v.w;
  ((f16x4*)h16)[i] = hv;
  ((f16x4*)x16)[i] = xv;
}

// C=512 variant, no x16 output
__global__ void bn2_apply_k(const float* __restrict__ x, const float* __restrict__ ss,
                            _Float16* __restrict__ h16) {
  const int i = blockIdx.x * 256 + threadIdx.x;      // < NTOT*512/4
  const float4 v = ((const float4*)x)[i];
  const int c4 = i & 127;
  const float4 sc = ((const float4*)ss)[c4];
  const float4 sh = ((const float4*)(ss + 512))[c4];
  f16x4 hv;
  hv[0] = (_Float16)gelu_f(v.x * sc.x + sh.x);
  hv[1] = (_Float16)gelu_f(v.y * sc.y + sh.y);
  hv[2] = (_Float16)gelu_f(v.z * sc.z + sh.z);
  hv[3] = (_Float16)gelu_f(v.w * sc.w + sh.w);
  ((f16x4*)h16)[i] = hv;
}

// ---------------- B preparation: Bt[n][k''] fp16, pre-swizzled ----------------
// Bt[n][k0 + (j ^ ((n&7)*8))] = B''[k0+j][n]  (k0 = 64-aligned block base)
__global__ void prep_bt_k(const float* __restrict__ W, const float* __restrict__ root,
                          const float* __restrict__ skipw, int rkEnd, int rootEnd, int Kfull,
                          _Float16* __restrict__ Bt) {
  __shared__ float tile[64][72];   // 288B row stride: keeps float4 stores 16B-aligned
  const int kb = blockIdx.x * 64, nb = blockIdx.y * 64;
  const int t = threadIdx.x;
  {
    const int i = t >> 2, j = (t & 3) * 16;
    const int kk = kb + i;
    const float* srow = (kk < rkEnd) ? (W + (size_t)kk * 512)
                      : ((kk < rootEnd) ? (root + (size_t)(kk - rkEnd) * 512)
                                        : (skipw + (size_t)(kk - rootEnd) * 512));
    #pragma unroll
    for (int q2 = 0; q2 < 4; ++q2) {
      float4 v = *(const float4*)(srow + nb + j + q2 * 4);
      *(float4*)&tile[i][j + q2 * 4] = v;
    }
  }
  __syncthreads();
  {
    const int nl = t >> 2, kg = (t & 3) * 16;
    const int n = nb + nl;
    const int s = (n & 7) << 3;        // element-XOR == byte-XOR (n&7)<<4
    #pragma unroll
    for (int g = 0; g < 2; ++g) {
      const int d0 = kg + g * 8;
      const int j0 = d0 ^ s;
      f16x8 o;
      #pragma unroll
      for (int u = 0; u < 8; ++u) o[u] = (_Float16)tile[j0 + u][nl];
      *(f16x8*)(Bt + (size_t)n * Kfull + kb + d0) = o;
    }
  }
}

// ---------------- fused gather-GEMM ----------------
// out[NT,512] = A'[NT,K''] @ B[K'',512] (+biases), where A' columns are:
//   [0, RK):        per-(rel,dst) mean of h16[src] rows (gathered from sorted edges)
//   [RK, ROOTEND):  h16 rows (root term)
//   [ROOTEND, +256) (HAS_SKIP): x16 rows (skip term)
template<int KH, int KSTEPS, int RK, int ROOTEND, bool HAS_SKIP>
__global__ __launch_bounds__(256, 2) void gemm_fused_k(
    const _Float16* __restrict__ h16, const _Float16* __restrict__ x16,
    const _Float16* __restrict__ Bt, const int* __restrict__ keyOff,
    const int* __restrict__ sortedSrc, const float* __restrict__ biasA,
    const float* __restrict__ biasB, float* __restrict__ out)
{
  constexpr int KFULL = HAS_SKIP ? (ROOTEND + 256) : ROOTEND;
  __shared__ _Float16 Alds[128 * 64];   // [row][k] fp16, XOR-swizzled
  __shared__ _Float16 Blds[256 * 64];   // [n][k] fp16, XOR-swizzled (pre-swizzled source)
  const int tid = threadIdx.x;
  const int lane = tid & 63;
  const int w = tid >> 6;
  const int n0 = blockIdx.x * 256;
  const int m0 = blockIdx.y * 128;
  const int arow = tid >> 1;
  const int ahalf = tid & 1;
  const int gi = m0 + arow;
  const int wr = w >> 1, wc = w & 1;

  f32x4 acc[4][8];
  #pragma unroll
  for (int m = 0; m < 4; ++m)
    #pragma unroll
    for (int n = 0; n < 8; ++n)
      acc[m][n] = f32x4{0.f, 0.f, 0.f, 0.f};

  for (int kt = 0; kt < KSTEPS; ++kt) {
    const int k0 = kt * 64;
    // ---- stage B: global_load_lds, linear LDS dest, pre-swizzled global source ----
    {
      const _Float16* gB = Bt + (size_t)(n0 + w * 64 + (lane >> 3)) * KFULL + k0 + (lane & 7) * 8;
      #pragma unroll
      for (int q = 0; q < 8; ++q) {
        __builtin_amdgcn_global_load_lds(
            (const __attribute__((address_space(1))) void*)(gB + (size_t)q * 8 * KFULL),
            (__attribute__((address_space(3))) void*)(Blds + (w * 64 + q * 8) * 64),
            16, 0, 0);
      }
    }
    // ---- stage A: 2 threads/row (32 cols each); gather-mean or direct copy ----
    {
      char* aldsrow = (char*)Alds + arow * 128;
      const int swz = (arow & 7) << 4;
      const int cb0 = ahalf * 32;
      if (k0 < RK) {
        const int r = k0 / KH;
        const int klocal = k0 - r * KH;
        const int bin = r * NTOT + gi;
        const int off0 = keyOff[bin];
        const int off1 = keyOff[bin + 1];
        const int cnt = off1 - off0;
        const float inv = (cnt > 0) ? (1.0f / (float)cnt) : 0.0f;
        float sacc[32];
        #pragma unroll
        for (int j = 0; j < 32; ++j) sacc[j] = 0.f;
        int e = off0;
        // 2 edges in flight: 8 independent 16B loads per round (MLP over latency)
        for (; e + 1 < off1; e += 2) {
          const int s0 = sortedSrc[e];
          const int s1 = sortedSrc[e + 1];
          const f16x8* p0 = (const f16x8*)(h16 + (size_t)s0 * KH + klocal + cb0);
          const f16x8* p1 = (const f16x8*)(h16 + (size_t)s1 * KH + klocal + cb0);
          f16x8 a[8];
          #pragma unroll
          for (int q = 0; q < 4; ++q) { a[q] = p0[q]; a[4 + q] = p1[q]; }
          #pragma unroll
          for (int q = 0; q < 4; ++q)
            #pragma unroll
            for (int j = 0; j < 8; ++j)
              sacc[q * 8 + j] += (float)a[q][j] + (float)a[4 + q][j];
        }
        if (e < off1) {
          const int s0 = sortedSrc[e];
          const f16x8* p0 = (const f16x8*)(h16 + (size_t)s0 * KH + klocal + cb0);
          #pragma unroll
          for (int q = 0; q < 4; ++q) {
            const f16x8 av = p0[q];
            #pragma unroll
            for (int j = 0; j < 8; ++j) sacc[q * 8 + j] += (float)av[j];
          }
        }
        #pragma unroll
        for (int q = 0; q < 4; ++q) {
          f16x8 o;
          #pragma unroll
          for (int j = 0; j < 8; ++j) o[j] = (_Float16)(sacc[q * 8 + j] * inv);
          *(f16x8*)(aldsrow + (((cb0 + q * 8) * 2) ^ swz)) = o;
        }
      } else {
        const _Float16* sp;
        if (!HAS_SKIP || k0 < ROOTEND) sp = h16 + (size_t)gi * KH + (k0 - RK);
        else                           sp = x16 + (size_t)gi * 256 + (k0 - ROOTEND);
        #pragma unroll
        for (int q = 0; q < 4; ++q) {
          const f16x8 v = *(const f16x8*)(sp + cb0 + q * 8);
          *(f16x8*)(aldsrow + (((cb0 + q * 8) * 2) ^ swz)) = v;
        }
      }
    }
    __syncthreads();
    // ---- compute: 4 waves, 64x128 wave tile, mfma 16x16x32 f16 ----
    #pragma unroll
    for (int kh2 = 0; kh2 < 2; ++kh2) {
      const int kByte = kh2 * 64 + ((lane >> 4) << 4);
      f16x8 af[4];
      #pragma unroll
      for (int m = 0; m < 4; ++m) {
        const int row = wr * 64 + m * 16 + (lane & 15);
        af[m] = *(const f16x8*)((const char*)Alds + row * 128 + (kByte ^ ((row & 7) << 4)));
      }
      #pragma unroll
      for (int n = 0; n < 8; ++n) {
        const int col = wc * 128 + n * 16 + (lane & 15);
        const f16x8 bf = *(const f16x8*)((const char*)Blds + col * 128 + (kByte ^ ((col & 7) << 4)));
        #pragma unroll
        for (int m = 0; m < 4; ++m)
          acc[m][n] = __builtin_amdgcn_mfma_f32_16x16x32_f16(af[m], bf, acc[m][n], 0, 0, 0);
      }
    }
    __syncthreads();
  }
  // ---- epilogue: C/D layout col=lane&15, row=(lane>>4)*4+q ----
  #pragma unroll
  for (int m = 0; m < 4; ++m) {
    const int grow = m0 + wr * 64 + m * 16 + ((lane >> 4) << 2);
    #pragma unroll
    for (int n = 0; n < 8; ++n) {
      const int gcol = n0 + wc * 128 + n * 16 + (lane & 15);
      float badd = biasA[gcol];
      if (HAS_SKIP) badd += biasB[gcol];
      #pragma unroll
      for (int q = 0; q < 4; ++q) {
        out[(size_t)(grow + q) * 512 + gcol] = acc[m][n][q] + badd;
      }
    }
  }
}

// ---------------- launch ----------------

extern "C" void kernel_launch(void* const* d_in, const int* in_sizes, int n_in,
                              void* d_out, int out_size, void* d_ws, size_t ws_size,
                              hipStream_t stream) {
  const float* x      = (const float*)d_in[0];
  const int*   ei     = (const int*)d_in[1];
  const int*   rel    = (const int*)d_in[2];
  const float* gamma1 = (const float*)d_in[3];
  const float* beta1  = (const float*)d_in[4];
  const float* W1     = (const float*)d_in[5];
  const float* root1  = (const float*)d_in[6];
  const float* b1     = (const float*)d_in[7];
  const float* gamma2 = (const float*)d_in[8];
  const float* beta2  = (const float*)d_in[9];
  const float* W2     = (const float*)d_in[10];
  const float* root2  = (const float*)d_in[11];
  const float* b2     = (const float*)d_in[12];
  const float* Wskip  = (const float*)d_in[13];
  const float* bskip  = (const float*)d_in[14];
  float* out = (float*)d_out;

  uintptr_t p = (uintptr_t)d_ws;
  auto carve = [&](size_t bytes) -> void* {
    void* r = (void*)p;
    p += (bytes + 255) & ~(size_t)255;
    return r;
  };
  int*      keyOff    = (int*)carve((size_t)(NB + 8) * 4);
  int*      cursor    = (int*)carve((size_t)(NB + 8) * 4);
  int*      partials  = (int*)carve(2048 * 4);
  int*      sortedSrc = (int*)carve((size_t)E_NUM * 4);
  float*    bnAcc1    = (float*)carve(512 * 4);     // contiguous with bnAcc2
  float*    bnAcc2    = (float*)carve(1024 * 4);
  float*    ss1       = (float*)carve(512 * 4);
  float*    ss2       = (float*)carve(1024 * 4);
  _Float16* Bt1       = (_Float16*)carve((size_t)512 * 11520 * 2);
  _Float16* Bt2       = (_Float16*)carve((size_t)512 * 23296 * 2);
  _Float16* x16       = (_Float16*)carve((size_t)NTOT * 256 * 2);
  _Float16* h16       = (_Float16*)carve((size_t)NTOT * 512 * 2);
  float*    out1      = (float*)carve((size_t)NTOT * 512 * 4);

  // zero hist bins + BN accumulators
  zero_int_k<<<(NB + 1 + 255) / 256, 256, 0, stream>>>(keyOff, NB + 1);
  zero_int_k<<<6, 256, 0, stream>>>((int*)bnAcc1, 1536);

  // B preparation (transpose + fp16 cast + LDS-swizzle baked in)
  prep_bt_k<<<dim3(180, 8), 256, 0, stream>>>(W1, root1, root1, 11264, 11520, 11520, Bt1);
  prep_bt_k<<<dim3(364, 8), 256, 0, stream>>>(W2, root2, Wskip, 22528, 23040, 23296, Bt2);

  // BN1 + GELU + fp16 casts
  bn_partial_k<256><<<250, 256, 0, stream>>>(x, bnAcc1);
  bn_final_k<<<1, 256, 0, stream>>>(bnAcc1, gamma1, beta1, ss1, 256);
  bn1_apply_k<<<8000, 256, 0, stream>>>(x, ss1, h16, x16);

  // counting sort of edges by (rel, dst)
  hist_k<<<2500, 256, 0, stream>>>(ei, rel, keyOff);
  scan1_k<<<1376, 256, 0, stream>>>(keyOff, partials, NB + 1);
  scan2_k<<<1, 256, 0, stream>>>(partials, 1376);
  scan3_k<<<1376, 256, 0, stream>>>(keyOff, partials, NB + 1);
  hipMemcpyAsync(cursor, keyOff, (size_t)NB * 4, hipMemcpyDeviceToDevice, stream);
  scatter_k<<<2500, 256, 0, stream>>>(ei, rel, cursor, sortedSrc);

  // layer 1: out1 = A'(h16) @ [W1;root1] + b1
  gemm_fused_k<256, 180, 11264, 11520, false><<<dim3(2, 250), 256, 0, stream>>>(
      h16, x16, Bt1, keyOff, sortedSrc, b1, b1, out1);

  // BN2 + GELU
  bn_partial_k<512><<<250, 256, 0, stream>>>(out1, bnAcc2);
  bn_final_k<<<1, 512, 0, stream>>>(bnAcc2, gamma2, beta2, ss2, 512);
  bn2_apply_k<<<16000, 256, 0, stream>>>(out1, ss2, h16);

  // layer 2: out = A'(h2) @ [W2;root2;Wskip] + b2 + bskip
  gemm_fused_k<512, 364, 22528, 23040, true><<<dim3(2, 250), 256, 0, stream>>>(
      h16, x16, Bt2, keyOff, sortedSrc, b2, bskip, out);
}

// Round 3
// 1735.864 us; speedup vs baseline: 1.3403x; 1.3403x over previous
//
#include <hip/hip_runtime.h>
#include <cstdint>

#define E_NUM 640000
#define NTOT 32000
#define RNUM 44
#define NB (RNUM*NTOT)   // 1,408,000 (rel,dst) bins

typedef _Float16 f16x8 __attribute__((ext_vector_type(8)));
typedef _Float16 f16x4 __attribute__((ext_vector_type(4)));
typedef float    f32x4 __attribute__((ext_vector_type(4)));

__device__ __forceinline__ float gelu_f(float v) {
  return 0.5f * v * (1.0f + erff(v * 0.70710678118654752f));
}

// ---------------- utility kernels ----------------

__global__ void zero_int_k(int* __restrict__ p, int n) {
  int i = blockIdx.x * 256 + threadIdx.x;
  if (i < n) p[i] = 0;
}

__global__ void hist_k(const int* __restrict__ ei, const int* __restrict__ rel,
                       int* __restrict__ hist) {
  int e = blockIdx.x * 256 + threadIdx.x;
  if (e < E_NUM) {
    int d = ei[E_NUM + e];
    int r = rel[e];
    atomicAdd(&hist[r * NTOT + d], 1);
  }
}

// exclusive scan, 1024 items/block, in-place; block totals -> partials
__global__ void scan1_k(int* __restrict__ data, int* __restrict__ partials, int n) {
  __shared__ int ws[4];
  const int t = threadIdx.x;
  const int base = blockIdx.x * 1024 + t * 4;
  int v0 = 0, v1 = 0, v2 = 0, v3 = 0;
  if (base + 3 < n) {
    int4 u = *(const int4*)(data + base);
    v0 = u.x; v1 = u.y; v2 = u.z; v3 = u.w;
  } else if (base < n) {
    v0 = data[base];
    if (base + 1 < n) v1 = data[base + 1];
    if (base + 2 < n) v2 = data[base + 2];
  }
  const int tsum = v0 + v1 + v2 + v3;
  int incl = tsum;
  #pragma unroll
  for (int off = 1; off < 64; off <<= 1) {
    int u = __shfl_up(incl, off, 64);
    if ((t & 63) >= off) incl += u;
  }
  if ((t & 63) == 63) ws[t >> 6] = incl;
  __syncthreads();
  int wofs = 0;
  #pragma unroll
  for (int wv = 0; wv < 3; ++wv) if (wv < (t >> 6)) wofs += ws[wv];
  const int excl = wofs + incl - tsum;
  if (base + 3 < n) {
    int4 o; o.x = excl; o.y = excl + v0; o.z = excl + v0 + v1; o.w = excl + v0 + v1 + v2;
    *(int4*)(data + base) = o;
  } else if (base < n) {
    data[base] = excl;
    if (base + 1 < n) data[base + 1] = excl + v0;
    if (base + 2 < n) data[base + 2] = excl + v0 + v1;
  }
  if (t == 255) partials[blockIdx.x] = wofs + incl;
}

// single-block exclusive scan of partials (n <= a few thousand)
__global__ void scan2_k(int* __restrict__ p, int n) {
  __shared__ int ws[4];
  __shared__ int carryS;
  const int t = threadIdx.x;
  if (t == 0) carryS = 0;
  for (int chunk = 0; chunk < n; chunk += 1024) {
    __syncthreads();
    const int carry = carryS;
    const int base = chunk + t * 4;
    int v0 = 0, v1 = 0, v2 = 0, v3 = 0;
    if (base     < n) v0 = p[base];
    if (base + 1 < n) v1 = p[base + 1];
    if (base + 2 < n) v2 = p[base + 2];
    if (base + 3 < n) v3 = p[base + 3];
    const int tsum = v0 + v1 + v2 + v3;
    int incl = tsum;
    #pragma unroll
    for (int off = 1; off < 64; off <<= 1) {
      int u = __shfl_up(incl, off, 64);
      if ((t & 63) >= off) incl += u;
    }
    if ((t & 63) == 63) ws[t >> 6] = incl;
    __syncthreads();
    int wofs = 0;
    #pragma unroll
    for (int wv = 0; wv < 3; ++wv) if (wv < (t >> 6)) wofs += ws[wv];
    const int excl = carry + wofs + incl - tsum;
    if (base     < n) p[base]     = excl;
    if (base + 1 < n) p[base + 1] = excl + v0;
    if (base + 2 < n) p[base + 2] = excl + v0 + v1;
    if (base + 3 < n) p[base + 3] = excl + v0 + v1 + v2;
    __syncthreads();
    if (t == 255) carryS = carry + wofs + incl;
  }
}

__global__ void scan3_k(int* __restrict__ data, const int* __restrict__ partials, int n) {
  const int base = blockIdx.x * 1024 + threadIdx.x * 4;
  const int pofs = partials[blockIdx.x];
  if (base + 3 < n) {
    int4 u = *(const int4*)(data + base);
    u.x += pofs; u.y += pofs; u.z += pofs; u.w += pofs;
    *(int4*)(data + base) = u;
  } else if (base < n) {
    data[base] += pofs;
    if (base + 1 < n) data[base + 1] += pofs;
    if (base + 2 < n) data[base + 2] += pofs;
  }
}

__global__ void scatter_k(const int* __restrict__ ei, const int* __restrict__ rel,
                          int* __restrict__ cursor, int* __restrict__ sortedSrc) {
  int e = blockIdx.x * 256 + threadIdx.x;
  if (e < E_NUM) {
    int s = ei[e], d = ei[E_NUM + e], r = rel[e];
    int pos = atomicAdd(&cursor[r * NTOT + d], 1);
    sortedSrc[pos] = s;
  }
}

// ---------------- batchnorm ----------------

template<int C>
__global__ void bn_partial_k(const float* __restrict__ x, float* __restrict__ acc) {
  const int t = threadIdx.x;
  const int r0 = blockIdx.x * 128;
  constexpr int CC = C / 256;
  float s[CC], q[CC];
  #pragma unroll
  for (int cc = 0; cc < CC; ++cc) { s[cc] = 0.f; q[cc] = 0.f; }
  for (int r = 0; r < 128; ++r) {
    const float* row = x + (size_t)(r0 + r) * C + t;
    #pragma unroll
    for (int cc = 0; cc < CC; ++cc) { float v = row[cc * 256]; s[cc] += v; q[cc] += v * v; }
  }
  #pragma unroll
  for (int cc = 0; cc < CC; ++cc) {
    atomicAdd(&acc[t + cc * 256], s[cc]);
    atomicAdd(&acc[C + t + cc * 256], q[cc]);
  }
}

__global__ void bn_final_k(const float* __restrict__ acc, const float* __restrict__ gamma,
                           const float* __restrict__ beta, float* __restrict__ ss, int C) {
  int c = threadIdx.x;
  if (c < C) {
    float mean = acc[c] * (1.0f / 32000.0f);
    float var  = acc[C + c] * (1.0f / 32000.0f) - mean * mean;
    float sc = gamma[c] / sqrtf(var + 1e-5f);
    ss[c] = sc;
    ss[C + c] = beta[c] - mean * sc;
  }
}

// h16 = fp16(gelu(bn(x))), x16 = fp16(x);  C=256
__global__ void bn1_apply_k(const float* __restrict__ x, const float* __restrict__ ss,
                            _Float16* __restrict__ h16, _Float16* __restrict__ x16) {
  const int i = blockIdx.x * 256 + threadIdx.x;      // < NTOT*256/4
  const float4 v = ((const float4*)x)[i];
  const int c4 = i & 63;
  const float4 sc = ((const float4*)ss)[c4];
  const float4 sh = ((const float4*)(ss + 256))[c4];
  f16x4 hv, xv;
  hv[0] = (_Float16)gelu_f(v.x * sc.x + sh.x);
  hv[1] = (_Float16)gelu_f(v.y * sc.y + sh.y);
  hv[2] = (_Float16)gelu_f(v.z * sc.z + sh.z);
  hv[3] = (_Float16)gelu_f(v.w * sc.w + sh.w);
  xv[0] = (_Float16)v.x; xv[1] = (_Float16)v.y; xv[2] = (_Float16)v.z; xv[3] = (_Float16)v.w;
  ((f16x4*)h16)[i] = hv;
  ((f16x4*)x16)[i] = xv;
}

// C=512 variant, no x16 output
__global__ void bn2_apply_k(const float* __restrict__ x, const float* __restrict__ ss,
                            _Float16* __restrict__ h16) {
  const int i = blockIdx.x * 256 + threadIdx.x;      // < NTOT*512/4
  const float4 v = ((const float4*)x)[i];
  const int c4 = i & 127;
  const float4 sc = ((const float4*)ss)[c4];
  const float4 sh = ((const float4*)(ss + 512))[c4];
  f16x4 hv;
  hv[0] = (_Float16)gelu_f(v.x * sc.x + sh.x);
  hv[1] = (_Float16)gelu_f(v.y * sc.y + sh.y);
  hv[2] = (_Float16)gelu_f(v.z * sc.z + sh.z);
  hv[3] = (_Float16)gelu_f(v.w * sc.w + sh.w);
  ((f16x4*)h16)[i] = hv;
}

// ---------------- B preparation: Bt[n][k''] fp16, pre-swizzled ----------------
// Bt[n][k0 + (j ^ ((n&7)*8))] = B''[k0+j][n]  (k0 = 64-aligned block base)
__global__ void prep_bt_k(const float* __restrict__ W, const float* __restrict__ root,
                          const float* __restrict__ skipw, int rkEnd, int rootEnd, int Kfull,
                          _Float16* __restrict__ Bt) {
  __shared__ float tile[64][72];   // 288B row stride: keeps float4 stores 16B-aligned
  const int kb = blockIdx.x * 64, nb = blockIdx.y * 64;
  const int t = threadIdx.x;
  {
    const int i = t >> 2, j = (t & 3) * 16;
    const int kk = kb + i;
    const float* srow = (kk < rkEnd) ? (W + (size_t)kk * 512)
                      : ((kk < rootEnd) ? (root + (size_t)(kk - rkEnd) * 512)
                                        : (skipw + (size_t)(kk - rootEnd) * 512));
    #pragma unroll
    for (int q2 = 0; q2 < 4; ++q2) {
      float4 v = *(const float4*)(srow + nb + j + q2 * 4);
      *(float4*)&tile[i][j + q2 * 4] = v;
    }
  }
  __syncthreads();
  {
    const int nl = t >> 2, kg = (t & 3) * 16;
    const int n = nb + nl;
    const int s = (n & 7) << 3;        // element-XOR == byte-XOR (n&7)<<4
    #pragma unroll
    for (int g = 0; g < 2; ++g) {
      const int d0 = kg + g * 8;
      const int j0 = d0 ^ s;
      f16x8 o;
      #pragma unroll
      for (int u = 0; u < 8; ++u) o[u] = (_Float16)tile[j0 + u][nl];
      *(f16x8*)(Bt + (size_t)n * Kfull + kb + d0) = o;
    }
  }
}

// ---------------- fused gather-GEMM ----------------
// Block tile: 64 rows (M) x 512 cols (full N), 512 threads = 8 waves (2x4).
// out[NT,512] = A'[NT,K''] @ B[K'',512] (+biases), A' columns:
//   [0, RK):        per-(rel,dst) mean of h16[src] rows (sorted-edge gather)
//   [RK, ROOTEND):  h16 rows (root term)
//   [ROOTEND, +256) (HAS_SKIP): x16 rows (skip term)
template<int KH, int KSTEPS, int RK, int ROOTEND, bool HAS_SKIP>
__global__ __launch_bounds__(512, 4) void gemm_fused_k(
    const _Float16* __restrict__ h16, const _Float16* __restrict__ x16,
    const _Float16* __restrict__ Bt, const int* __restrict__ keyOff,
    const int* __restrict__ sortedSrc, const float* __restrict__ biasA,
    const float* __restrict__ biasB, float* __restrict__ out)
{
  constexpr int KFULL = HAS_SKIP ? (ROOTEND + 256) : ROOTEND;
  constexpr int LOG2KH = (KH == 256) ? 8 : 9;
  __shared__ _Float16 Alds[64 * 64];    // [row][k] fp16, XOR-swizzled
  __shared__ _Float16 Blds[512 * 64];   // [n][k] fp16, XOR-swizzled (pre-swizzled source)
  const int tid = threadIdx.x;
  const int lane = tid & 63;
  const int w = tid >> 6;              // 0..7
  const int wr = w >> 2, wc = w & 3;   // wave grid 2(m) x 4(n)
  const int m0 = blockIdx.x * 64;
  const int arow = tid >> 3;           // 0..63: A row this thread stages
  const int tsub = tid & 7;            // 8 threads/row, 8 cols each
  const int tcol = tsub * 8;
  const int gi = m0 + arow;

  f32x4 acc[2][8];
  #pragma unroll
  for (int m = 0; m < 2; ++m)
    #pragma unroll
    for (int n = 0; n < 8; ++n)
      acc[m][n] = f32x4{0.f, 0.f, 0.f, 0.f};

  // per-relation cached gather state (refreshed when klocal==0)
  int off0 = 0, cnt = 0;
  int c0 = 0, c1 = 0, c2 = 0;
  float inv = 0.f;

  char* const aldsrow = (char*)Alds + arow * 128;
  const int swz = (arow & 7) << 4;

  for (int kt = 0; kt < KSTEPS; ++kt) {
    const int k0 = kt * 64;
    // ---- stage B: wave w stages cols [w*64, w*64+64); linear LDS dest ----
    {
      const _Float16* gB = Bt + (size_t)(w * 64 + (lane >> 3)) * KFULL + k0 + (lane & 7) * 8;
      #pragma unroll
      for (int q = 0; q < 8; ++q) {
        __builtin_amdgcn_global_load_lds(
            (const __attribute__((address_space(1))) void*)(gB + (size_t)q * 8 * KFULL),
            (__attribute__((address_space(3))) void*)(Blds + (w * 64 + q * 8) * 64),
            16, 0, 0);
      }
    }
    // ---- stage A: 8 threads/row, 8 cols each ----
    if (k0 < RK) {
      const int klocal = k0 & (KH - 1);
      if (klocal == 0) {              // entering a new relation: refresh cache
        const int r = k0 >> LOG2KH;
        const int bin = r * NTOT + gi;
        off0 = keyOff[bin];
        const int o1 = keyOff[bin + 1];
        cnt = o1 - off0;
        inv = (cnt > 0) ? (1.0f / (float)cnt) : 0.0f;
        if (cnt > 0) c0 = sortedSrc[off0];
        if (cnt > 1) c1 = sortedSrc[off0 + 1];
        if (cnt > 2) c2 = sortedSrc[off0 + 2];
      }
      if (cnt == 0) {
        *(f16x8*)(aldsrow + ((tcol * 2) ^ swz)) = f16x8{};
      } else {
        f16x8 a0, a1, a2;
        a0 = *(const f16x8*)(h16 + (size_t)c0 * KH + klocal + tcol);
        if (cnt > 1) a1 = *(const f16x8*)(h16 + (size_t)c1 * KH + klocal + tcol);
        if (cnt > 2) a2 = *(const f16x8*)(h16 + (size_t)c2 * KH + klocal + tcol);
        float sacc[8];
        #pragma unroll
        for (int j = 0; j < 8; ++j) sacc[j] = (float)a0[j];
        if (cnt > 1) {
          #pragma unroll
          for (int j = 0; j < 8; ++j) sacc[j] += (float)a1[j];
        }
        if (cnt > 2) {
          #pragma unroll
          for (int j = 0; j < 8; ++j) sacc[j] += (float)a2[j];
        }
        for (int e = off0 + 3; e < off0 + cnt; ++e) {   // rare (P < 0.2%)
          const int s = sortedSrc[e];
          const f16x8 av = *(const f16x8*)(h16 + (size_t)s * KH + klocal + tcol);
          #pragma unroll
          for (int j = 0; j < 8; ++j) sacc[j] += (float)av[j];
        }
        f16x8 o;
        #pragma unroll
        for (int j = 0; j < 8; ++j) o[j] = (_Float16)(sacc[j] * inv);
        *(f16x8*)(aldsrow + ((tcol * 2) ^ swz)) = o;
      }
    } else {
      const _Float16* sp;
      if (!HAS_SKIP || k0 < ROOTEND) sp = h16 + (size_t)gi * KH + (k0 - RK);
      else                           sp = x16 + (size_t)gi * 256 + (k0 - ROOTEND);
      const f16x8 v = *(const f16x8*)(sp + tcol);
      *(f16x8*)(aldsrow + ((tcol * 2) ^ swz)) = v;
    }
    __syncthreads();
    // ---- compute: wave tile 32x128, mfma 16x16x32 f16 ----
    #pragma unroll
    for (int kh2 = 0; kh2 < 2; ++kh2) {
      const int kByte = kh2 * 64 + ((lane >> 4) << 4);
      f16x8 af[2];
      #pragma unroll
      for (int m = 0; m < 2; ++m) {
        const int row = wr * 32 + m * 16 + (lane & 15);
        af[m] = *(const f16x8*)((const char*)Alds + row * 128 + (kByte ^ ((row & 7) << 4)));
      }
      #pragma unroll
      for (int n = 0; n < 8; ++n) {
        const int col = wc * 128 + n * 16 + (lane & 15);
        const f16x8 bf = *(const f16x8*)((const char*)Blds + col * 128 + (kByte ^ ((col & 7) << 4)));
        #pragma unroll
        for (int m = 0; m < 2; ++m)
          acc[m][n] = __builtin_amdgcn_mfma_f32_16x16x32_f16(af[m], bf, acc[m][n], 0, 0, 0);
      }
    }
    __syncthreads();
  }
  // ---- epilogue: C/D layout col=lane&15, row=(lane>>4)*4+q ----
  #pragma unroll
  for (int m = 0; m < 2; ++m) {
    const int grow = m0 + wr * 32 + m * 16 + ((lane >> 4) << 2);
    #pragma unroll
    for (int n = 0; n < 8; ++n) {
      const int gcol = wc * 128 + n * 16 + (lane & 15);
      float badd = biasA[gcol];
      if (HAS_SKIP) badd += biasB[gcol];
      #pragma unroll
      for (int q = 0; q < 4; ++q) {
        out[(size_t)(grow + q) * 512 + gcol] = acc[m][n][q] + badd;
      }
    }
  }
}

// ---------------- launch ----------------

extern "C" void kernel_launch(void* const* d_in, const int* in_sizes, int n_in,
                              void* d_out, int out_size, void* d_ws, size_t ws_size,
                              hipStream_t stream) {
  const float* x      = (const float*)d_in[0];
  const int*   ei     = (const int*)d_in[1];
  const int*   rel    = (const int*)d_in[2];
  const float* gamma1 = (const float*)d_in[3];
  const float* beta1  = (const float*)d_in[4];
  const float* W1     = (const float*)d_in[5];
  const float* root1  = (const float*)d_in[6];
  const float* b1     = (const float*)d_in[7];
  const float* gamma2 = (const float*)d_in[8];
  const float* beta2  = (const float*)d_in[9];
  const float* W2     = (const float*)d_in[10];
  const float* root2  = (const float*)d_in[11];
  const float* b2     = (const float*)d_in[12];
  const float* Wskip  = (const float*)d_in[13];
  const float* bskip  = (const float*)d_in[14];
  float* out = (float*)d_out;

  uintptr_t p = (uintptr_t)d_ws;
  auto carve = [&](size_t bytes) -> void* {
    void* r = (void*)p;
    p += (bytes + 255) & ~(size_t)255;
    return r;
  };
  int*      keyOff    = (int*)carve((size_t)(NB + 8) * 4);
  int*      cursor    = (int*)carve((size_t)(NB + 8) * 4);
  int*      partials  = (int*)carve(2048 * 4);
  int*      sortedSrc = (int*)carve((size_t)E_NUM * 4);
  float*    bnAcc1    = (float*)carve(512 * 4);     // contiguous with bnAcc2
  float*    bnAcc2    = (float*)carve(1024 * 4);
  float*    ss1       = (float*)carve(512 * 4);
  float*    ss2       = (float*)carve(1024 * 4);
  _Float16* Bt1       = (_Float16*)carve((size_t)512 * 11520 * 2);
  _Float16* Bt2       = (_Float16*)carve((size_t)512 * 23296 * 2);
  _Float16* x16       = (_Float16*)carve((size_t)NTOT * 256 * 2);
  _Float16* h16       = (_Float16*)carve((size_t)NTOT * 512 * 2);
  float*    out1      = (float*)carve((size_t)NTOT * 512 * 4);

  // zero hist bins + BN accumulators
  zero_int_k<<<(NB + 1 + 255) / 256, 256, 0, stream>>>(keyOff, NB + 1);
  zero_int_k<<<6, 256, 0, stream>>>((int*)bnAcc1, 1536);

  // B preparation (transpose + fp16 cast + LDS-swizzle baked in)
  prep_bt_k<<<dim3(180, 8), 256, 0, stream>>>(W1, root1, root1, 11264, 11520, 11520, Bt1);
  prep_bt_k<<<dim3(364, 8), 256, 0, stream>>>(W2, root2, Wskip, 22528, 23040, 23296, Bt2);

  // BN1 + GELU + fp16 casts
  bn_partial_k<256><<<250, 256, 0, stream>>>(x, bnAcc1);
  bn_final_k<<<1, 256, 0, stream>>>(bnAcc1, gamma1, beta1, ss1, 256);
  bn1_apply_k<<<8000, 256, 0, stream>>>(x, ss1, h16, x16);

  // counting sort of edges by (rel, dst)
  hist_k<<<2500, 256, 0, stream>>>(ei, rel, keyOff);
  scan1_k<<<1376, 256, 0, stream>>>(keyOff, partials, NB + 1);
  scan2_k<<<1, 256, 0, stream>>>(partials, 1376);
  scan3_k<<<1376, 256, 0, stream>>>(keyOff, partials, NB + 1);
  hipMemcpyAsync(cursor, keyOff, (size_t)NB * 4, hipMemcpyDeviceToDevice, stream);
  scatter_k<<<2500, 256, 0, stream>>>(ei, rel, cursor, sortedSrc);

  // layer 1: out1 = A'(h16) @ [W1;root1] + b1
  gemm_fused_k<256, 180, 11264, 11520, false><<<500, 512, 0, stream>>>(
      h16, x16, Bt1, keyOff, sortedSrc, b1, b1, out1);

  // BN2 + GELU
  bn_partial_k<512><<<250, 256, 0, stream>>>(out1, bnAcc2);
  bn_final_k<<<1, 512, 0, stream>>>(bnAcc2, gamma2, beta2, ss2, 512);
  bn2_apply_k<<<16000, 256, 0, stream>>>(out1, ss2, h16);

  // layer 2: out = A'(h2) @ [W2;root2;Wskip] + b2 + bskip
  gemm_fused_k<512, 364, 22528, 23040, true><<<500, 512, 0, stream>>>(
      h16, x16, Bt2, keyOff, sortedSrc, b2, bskip, out);
}